// Round 3
// baseline (179.147 us; speedup 1.0000x reference)
//
#include <hip/hip_runtime.h>
#include <hip/hip_bf16.h>
#include <hip/hip_cooperative_groups.h>

namespace cg = cooperative_groups;

// Problem constants
static constexpr int FEAT_  = 3136;   // K of GEMM1
static constexpr int KSTEPS = 98;     // 3136 / 32
static constexpr int RSTR   = 300;    // x row stride (proposals per batch)
static constexpr int SROWS  = 128;    // SELECTED_PROPOSAL
static constexpr int HID    = 64;     // hidden
static constexpr int NCLS   = 21;     // classes
static constexpr int NFRAG  = KSTEPS * 4 * 64;   // 25088 W1 fragments

typedef __attribute__((ext_vector_type(8))) short bf16x8;
typedef __attribute__((ext_vector_type(4))) float f32x4;

// W1 pre-packed in MFMA B-fragment order: [kstep][ntile][lane] -> 8 bf16.
__device__ bf16x8 g_w1p[NFRAG];

__device__ __forceinline__ short f2bf(float f) {
    union { float f; unsigned u; } v; v.f = f;
    unsigned r = v.u + 0x7fffu + ((v.u >> 16) & 1u);   // round-to-nearest-even
    return (short)(r >> 16);
}

// Single cooperative kernel: phase 1 packs W1, grid-sync, phase 2 main.
// 512 blocks x 512 threads, 2 blocks/CU (forced by launch_bounds VGPR cap).
__global__ __launch_bounds__(512, 4) void fused_all(
    const float* __restrict__ x,  const float* __restrict__ W1,
    const float* __restrict__ b1, const float* __restrict__ W2,
    const float* __restrict__ b2, const int* __restrict__ keep,
    float* __restrict__ out)
{
    const int tid = threadIdx.x;

    // ---------- phase 1: pack W1 (49 frags per block, 512*49 = 25088) ----------
    if (tid < NFRAG / 512) {
        int t = blockIdx.x * (NFRAG / 512) + tid;
        int lane = t & 63;
        int nt   = (t >> 6) & 3;
        int ks   = t >> 8;
        int col  = nt * 16 + (lane & 15);
        int k0   = ks * 32 + (lane >> 4) * 8;
        bf16x8 v;
        #pragma unroll
        for (int j = 0; j < 8; ++j) v[j] = f2bf(W1[(k0 + j) * HID + col]);
        g_w1p[t] = v;
    }
    __threadfence();
    cg::this_grid().sync();

    // ---------- phase 2: fused classifier ----------
    const int lane = tid & 63;
    const int wv   = tid >> 6;                 // 0..7 (K-split)
    const int row_base = blockIdx.x * 16;      // flat (b*128 + s) row
    const int b      = row_base >> 7;
    const int s_base = row_base & 127;

    float* outp = out + row_base * NCLS;
    const int limit = min(keep[b], SROWS);

    // Whole 16-row group masked out -> just write zeros, skip all loads.
    if (s_base >= limit) {
        for (int i = tid; i < 16 * NCLS; i += 512) outp[i] = 0.f;
        return;
    }

    __shared__ float hp[8][16][HID + 1];   // per-wave K-partial sums
    __shared__ float hf[16][HID + 2];      // reduced h
    __shared__ float w2s[HID * NCLS];

    for (int i = tid; i < HID * NCLS; i += 512) w2s[i] = W2[i];

    // K-range for this wave: [ks0, ks1)
    const int ks0 = (wv * KSTEPS) >> 3;
    const int ks1 = ((wv + 1) * KSTEPS) >> 3;

    // A-frag: lane supplies row (lane&15), k-chunk (lane>>4)*8.
    // Masked rows clamp to an already-read row: same addresses -> L1 hits,
    // no extra HBM lines.
    const int s_row = min(s_base + (lane & 15), limit - 1);
    const float* xp = x + (b * RSTR + s_row) * FEAT_ + ((lane >> 4) * 8);
    const bf16x8* wp = g_w1p + lane;           // frag (ks*4+nq)*64 + lane

    f32x4 acc0 = {0.f,0.f,0.f,0.f}, acc1 = {0.f,0.f,0.f,0.f};
    f32x4 acc2 = {0.f,0.f,0.f,0.f}, acc3 = {0.f,0.f,0.f,0.f};

    #pragma unroll 2
    for (int ks = ks0; ks < ks1; ++ks) {
        float4 a0 = *(const float4*)(xp + ks * 32);
        float4 a1 = *(const float4*)(xp + ks * 32 + 4);
        bf16x8 bv0 = wp[(ks * 4 + 0) * 64];
        bf16x8 bv1 = wp[(ks * 4 + 1) * 64];
        bf16x8 bv2 = wp[(ks * 4 + 2) * 64];
        bf16x8 bv3 = wp[(ks * 4 + 3) * 64];
        bf16x8 af;
        af[0] = f2bf(a0.x); af[1] = f2bf(a0.y);
        af[2] = f2bf(a0.z); af[3] = f2bf(a0.w);
        af[4] = f2bf(a1.x); af[5] = f2bf(a1.y);
        af[6] = f2bf(a1.z); af[7] = f2bf(a1.w);
        acc0 = __builtin_amdgcn_mfma_f32_16x16x32_bf16(af, bv0, acc0, 0, 0, 0);
        acc1 = __builtin_amdgcn_mfma_f32_16x16x32_bf16(af, bv1, acc1, 0, 0, 0);
        acc2 = __builtin_amdgcn_mfma_f32_16x16x32_bf16(af, bv2, acc2, 0, 0, 0);
        acc3 = __builtin_amdgcn_mfma_f32_16x16x32_bf16(af, bv3, acc3, 0, 0, 0);
    }

    // D layout: col = lane&15 (+16*nq), row = (lane>>4)*4 + r
    const int r0 = (lane >> 4) * 4;
    const int c0 = lane & 15;
    #pragma unroll
    for (int r = 0; r < 4; ++r) {
        hp[wv][r0 + r][c0     ] = acc0[r];
        hp[wv][r0 + r][c0 + 16] = acc1[r];
        hp[wv][r0 + r][c0 + 32] = acc2[r];
        hp[wv][r0 + r][c0 + 48] = acc3[r];
    }
    __syncthreads();

    // Reduce over the 8 K-partials, add b1, leaky relu #1
    for (int e = tid; e < 16 * HID; e += 512) {
        int row = e >> 6, col = e & 63;
        float v = b1[col];
        #pragma unroll
        for (int p = 0; p < 8; ++p) v += hp[p][row][col];
        hf[row][col] = (v >= 0.f) ? v : 0.1f * v;
    }
    __syncthreads();

    // GEMM2: [16 x 64] @ [64 x 21] + b2, leaky, keep_count mask
    for (int idx = tid; idx < 16 * NCLS; idx += 512) {
        int r = idx / NCLS;
        int c = idx - r * NCLS;
        float a2 = b2[c];
        #pragma unroll 8
        for (int col = 0; col < HID; ++col)
            a2 += hf[r][col] * w2s[col * NCLS + c];
        a2 = (a2 >= 0.f) ? a2 : 0.1f * a2;        // leaky relu #2
        outp[idx] = (s_base + r < limit) ? a2 : 0.f;
    }
}

extern "C" void kernel_launch(void* const* d_in, const int* in_sizes, int n_in,
                              void* d_out, int out_size, void* d_ws, size_t ws_size,
                              hipStream_t stream) {
    const float* x    = (const float*)d_in[0];
    const float* W1   = (const float*)d_in[1];
    const float* b1   = (const float*)d_in[2];
    const float* W2   = (const float*)d_in[3];
    const float* b2   = (const float*)d_in[4];
    const int*   keep = (const int*)d_in[5];
    float* out = (float*)d_out;

    void* args[] = { (void*)&x, (void*)&W1, (void*)&b1, (void*)&W2,
                     (void*)&b2, (void*)&keep, (void*)&out };
    hipLaunchCooperativeKernel((const void*)fused_all,
                               dim3((64 * SROWS) / 16), dim3(512),
                               args, 0, stream);
}

// Round 4
// 31.839 us; speedup vs baseline: 5.6267x; 5.6267x over previous
//
#include <hip/hip_runtime.h>
#include <hip/hip_bf16.h>

// Problem constants
static constexpr int FEAT_  = 3136;   // K of GEMM1
static constexpr int KSTEPS = 98;     // 3136 / 32
static constexpr int RSTR   = 300;    // x row stride (proposals per batch)
static constexpr int SROWS  = 128;    // SELECTED_PROPOSAL
static constexpr int HID    = 64;     // hidden
static constexpr int NCLS   = 21;     // classes

typedef __attribute__((ext_vector_type(8))) short bf16x8;
typedef __attribute__((ext_vector_type(4))) float f32x4;

// W1 pre-packed in MFMA B-fragment order: [kstep][ntile][lane] -> 8 bf16.
__device__ bf16x8 g_w1p[KSTEPS * 4 * 64];

__device__ __forceinline__ short f2bf(float f) {
    union { float f; unsigned u; } v; v.f = f;
    unsigned r = v.u + 0x7fffu + ((v.u >> 16) & 1u);   // round-to-nearest-even
    return (short)(r >> 16);
}

// One thread per B-fragment (8 bf16): t = (ks*4 + nt)*64 + lane
__global__ __launch_bounds__(256) void pack_w1(const float* __restrict__ W1) {
    int t = blockIdx.x * 256 + threadIdx.x;        // 0 .. 25087
    int lane = t & 63;
    int nt   = (t >> 6) & 3;
    int ks   = t >> 8;
    int col  = nt * 16 + (lane & 15);              // B col = lane % 16
    int k0   = ks * 32 + (lane >> 4) * 8;          // B k   = (lane/16)*8 + j
    bf16x8 v;
    #pragma unroll
    for (int j = 0; j < 8; ++j) v[j] = f2bf(W1[(k0 + j) * HID + col]);
    g_w1p[t] = v;
}

// One block = 16 output rows, 512 threads. 8 waves split the K dimension
// (x read exactly once); each wave computes all 4 hidden-column quarters.
// 512 blocks -> 2 blocks/CU -> 16 waves/CU = 4 waves/SIMD.
__global__ __launch_bounds__(512) void fused_main(
    const float* __restrict__ x,  const float* __restrict__ b1,
    const float* __restrict__ W2, const float* __restrict__ b2,
    const int*  __restrict__ keep, float* __restrict__ out)
{
    const int tid  = threadIdx.x;
    const int lane = tid & 63;
    const int wv   = tid >> 6;                 // 0..7 (K-split)
    const int row_base = blockIdx.x * 16;      // flat (b*128 + s) row
    const int b      = row_base >> 7;
    const int s_base = row_base & 127;

    float* outp = out + row_base * NCLS;
    const int limit = min(keep[b], SROWS);

    // Whole 16-row group masked out -> just write zeros, skip all loads.
    if (s_base >= limit) {
        for (int i = tid; i < 16 * NCLS; i += 512) outp[i] = 0.f;
        return;
    }

    __shared__ float hp[8][16][HID + 1];   // per-wave K-partial sums
    __shared__ float hf[16][HID + 2];      // reduced h
    __shared__ float w2s[HID * NCLS];

    for (int i = tid; i < HID * NCLS; i += 512) w2s[i] = W2[i];

    // K-range for this wave: [ks0, ks1)
    const int ks0 = (wv * KSTEPS) >> 3;
    const int ks1 = ((wv + 1) * KSTEPS) >> 3;

    // A-frag: lane supplies row (lane&15), k-chunk (lane>>4)*8.
    // Masked rows clamp to an already-read row: same addresses -> L1 hits.
    const int s_row = min(s_base + (lane & 15), limit - 1);
    const float* xp = x + (b * RSTR + s_row) * FEAT_ + ((lane >> 4) * 8);
    const bf16x8* wp = g_w1p + lane;           // frag (ks*4+nq)*64 + lane

    f32x4 acc0 = {0.f,0.f,0.f,0.f}, acc1 = {0.f,0.f,0.f,0.f};
    f32x4 acc2 = {0.f,0.f,0.f,0.f}, acc3 = {0.f,0.f,0.f,0.f};

    #pragma unroll 2
    for (int ks = ks0; ks < ks1; ++ks) {
        float4 a0 = *(const float4*)(xp + ks * 32);
        float4 a1 = *(const float4*)(xp + ks * 32 + 4);
        bf16x8 bv0 = wp[(ks * 4 + 0) * 64];
        bf16x8 bv1 = wp[(ks * 4 + 1) * 64];
        bf16x8 bv2 = wp[(ks * 4 + 2) * 64];
        bf16x8 bv3 = wp[(ks * 4 + 3) * 64];
        bf16x8 af;
        af[0] = f2bf(a0.x); af[1] = f2bf(a0.y);
        af[2] = f2bf(a0.z); af[3] = f2bf(a0.w);
        af[4] = f2bf(a1.x); af[5] = f2bf(a1.y);
        af[6] = f2bf(a1.z); af[7] = f2bf(a1.w);
        acc0 = __builtin_amdgcn_mfma_f32_16x16x32_bf16(af, bv0, acc0, 0, 0, 0);
        acc1 = __builtin_amdgcn_mfma_f32_16x16x32_bf16(af, bv1, acc1, 0, 0, 0);
        acc2 = __builtin_amdgcn_mfma_f32_16x16x32_bf16(af, bv2, acc2, 0, 0, 0);
        acc3 = __builtin_amdgcn_mfma_f32_16x16x32_bf16(af, bv3, acc3, 0, 0, 0);
    }

    // D layout: col = lane&15 (+16*nq), row = (lane>>4)*4 + r
    const int r0 = (lane >> 4) * 4;
    const int c0 = lane & 15;
    #pragma unroll
    for (int r = 0; r < 4; ++r) {
        hp[wv][r0 + r][c0     ] = acc0[r];
        hp[wv][r0 + r][c0 + 16] = acc1[r];
        hp[wv][r0 + r][c0 + 32] = acc2[r];
        hp[wv][r0 + r][c0 + 48] = acc3[r];
    }
    __syncthreads();

    // Reduce over the 8 K-partials, add b1, leaky relu #1
    for (int e = tid; e < 16 * HID; e += 512) {
        int row = e >> 6, col = e & 63;
        float v = b1[col];
        #pragma unroll
        for (int p = 0; p < 8; ++p) v += hp[p][row][col];
        hf[row][col] = (v >= 0.f) ? v : 0.1f * v;
    }
    __syncthreads();

    // GEMM2: [16 x 64] @ [64 x 21] + b2, leaky, keep_count mask
    for (int idx = tid; idx < 16 * NCLS; idx += 512) {
        int r = idx / NCLS;
        int c = idx - r * NCLS;
        float a2 = b2[c];
        #pragma unroll 8
        for (int col = 0; col < HID; ++col)
            a2 += hf[r][col] * w2s[col * NCLS + c];
        a2 = (a2 >= 0.f) ? a2 : 0.1f * a2;        // leaky relu #2
        outp[idx] = (s_base + r < limit) ? a2 : 0.f;
    }
}

extern "C" void kernel_launch(void* const* d_in, const int* in_sizes, int n_in,
                              void* d_out, int out_size, void* d_ws, size_t ws_size,
                              hipStream_t stream) {
    const float* x    = (const float*)d_in[0];
    const float* W1   = (const float*)d_in[1];
    const float* b1   = (const float*)d_in[2];
    const float* W2   = (const float*)d_in[3];
    const float* b2   = (const float*)d_in[4];
    const int*   keep = (const int*)d_in[5];
    float* out = (float*)d_out;

    hipLaunchKernelGGL(pack_w1,    dim3(KSTEPS), dim3(256), 0, stream, W1);
    hipLaunchKernelGGL(fused_main, dim3((64 * SROWS) / 16), dim3(512), 0, stream,
                       x, b1, W2, b2, keep, out);
}

// Round 5
// 29.026 us; speedup vs baseline: 6.1720x; 1.0969x over previous
//
#include <hip/hip_runtime.h>
#include <hip/hip_bf16.h>

// Problem constants
static constexpr int FEAT_  = 3136;   // K of GEMM1
static constexpr int KSTEPS = 98;     // 3136 / 32
static constexpr int RSTR   = 300;    // x row stride (proposals per batch)
static constexpr int SROWS  = 128;    // SELECTED_PROPOSAL
static constexpr int HID    = 64;     // hidden
static constexpr int NCLS   = 21;     // classes
static constexpr int BM     = 32;     // rows per block

typedef __attribute__((ext_vector_type(8))) short bf16x8;
typedef __attribute__((ext_vector_type(4))) float f32x4;

// W1 pre-packed in MFMA B-fragment order with a k-permutation chosen so the
// matching A loads are two fully-dense 64B line groups per row:
//   frag elem j<4 : k = ks*32 + g*4 + j        (g = lane>>4)
//   frag elem j>=4: k = ks*32 + 16 + g*4 + j-4
__device__ bf16x8 g_w1p[KSTEPS * 4 * 64];

__device__ __forceinline__ short f2bf(float f) {
    union { float f; unsigned u; } v; v.f = f;
    unsigned r = v.u + 0x7fffu + ((v.u >> 16) & 1u);   // round-to-nearest-even
    return (short)(r >> 16);
}

// One thread per B-fragment (8 bf16): t = (ks*4 + nt)*64 + lane
__global__ __launch_bounds__(256) void pack_w1(const float* __restrict__ W1) {
    int t = blockIdx.x * 256 + threadIdx.x;        // 0 .. 25087
    int lane = t & 63;
    int nt   = (t >> 6) & 3;
    int ks   = t >> 8;
    int col  = nt * 16 + (lane & 15);
    int g    = lane >> 4;
    int k0   = ks * 32 + g * 4;
    bf16x8 v;
    #pragma unroll
    for (int j = 0; j < 4; ++j) v[j]     = f2bf(W1[(k0 + j) * HID + col]);
    #pragma unroll
    for (int j = 0; j < 4; ++j) v[4 + j] = f2bf(W1[(k0 + 16 + j) * HID + col]);
    g_w1p[t] = v;
}

// One block = 32 output rows, 512 threads = 8 waves. Waves split K 8 ways;
// each wave computes BOTH 16-row m-tiles x all 4 n-quarters, so every
// packed-W1 fragment is read exactly once per block (w1p traffic halved
// vs BM=16) and x is read exactly once grid-wide.
__global__ __launch_bounds__(512) void fused_main(
    const float* __restrict__ x,  const float* __restrict__ b1,
    const float* __restrict__ W2, const float* __restrict__ b2,
    const int*  __restrict__ keep, float* __restrict__ out)
{
    const int tid  = threadIdx.x;
    const int lane = tid & 63;
    const int wv   = tid >> 6;                 // 0..7 = K-part
    const int row_base = blockIdx.x * BM;      // flat (b*128 + s) row
    const int b      = row_base >> 7;
    const int s_base = row_base & 127;

    float* outp = out + row_base * NCLS;
    const int limit = min(keep[b], SROWS);

    // Whole 32-row group masked out -> just write zeros, skip all loads.
    if (s_base >= limit) {
        for (int i = tid; i < BM * NCLS; i += 512) outp[i] = 0.f;
        return;
    }

    __shared__ float hp[8][BM][HID + 1];   // per-wave K-partial sums (66.5 KB)
    __shared__ float hf[BM][HID + 2];      // reduced h
    __shared__ float w2s[HID * NCLS];

    for (int i = tid; i < HID * NCLS; i += 512) w2s[i] = W2[i];

    // K-range for this wave: [ks0, ks1)
    const int ks0 = (wv * KSTEPS) >> 3;
    const int ks1 = ((wv + 1) * KSTEPS) >> 3;

    const int g = lane >> 4;            // k-group
    const int r = lane & 15;            // row within m-tile / B col
    // Masked rows clamp to an already-read row: same addresses -> L1 hits.
    const int row0 = min(s_base + r,      limit - 1);
    const int row1 = min(s_base + 16 + r, limit - 1);
    const float* xp0 = x + (b * RSTR + row0) * FEAT_ + g * 4;
    const float* xp1 = x + (b * RSTR + row1) * FEAT_ + g * 4;
    const bf16x8* wp = g_w1p + lane;    // frag (ks*4+nq)*64 + lane

    f32x4 a00 = {0,0,0,0}, a01 = {0,0,0,0}, a02 = {0,0,0,0}, a03 = {0,0,0,0};
    f32x4 a10 = {0,0,0,0}, a11 = {0,0,0,0}, a12 = {0,0,0,0}, a13 = {0,0,0,0};

    #pragma unroll 2
    for (int ks = ks0; ks < ks1; ++ks) {
        // Two dense 64B-line loads per row: floats [g*4, g*4+4) and +16.
        float4 p0a = *(const float4*)(xp0 + ks * 32);
        float4 p0b = *(const float4*)(xp0 + ks * 32 + 16);
        float4 p1a = *(const float4*)(xp1 + ks * 32);
        float4 p1b = *(const float4*)(xp1 + ks * 32 + 16);
        bf16x8 bv0 = wp[(ks * 4 + 0) * 64];
        bf16x8 bv1 = wp[(ks * 4 + 1) * 64];
        bf16x8 bv2 = wp[(ks * 4 + 2) * 64];
        bf16x8 bv3 = wp[(ks * 4 + 3) * 64];
        bf16x8 af0, af1;
        af0[0]=f2bf(p0a.x); af0[1]=f2bf(p0a.y); af0[2]=f2bf(p0a.z); af0[3]=f2bf(p0a.w);
        af0[4]=f2bf(p0b.x); af0[5]=f2bf(p0b.y); af0[6]=f2bf(p0b.z); af0[7]=f2bf(p0b.w);
        af1[0]=f2bf(p1a.x); af1[1]=f2bf(p1a.y); af1[2]=f2bf(p1a.z); af1[3]=f2bf(p1a.w);
        af1[4]=f2bf(p1b.x); af1[5]=f2bf(p1b.y); af1[6]=f2bf(p1b.z); af1[7]=f2bf(p1b.w);
        a00 = __builtin_amdgcn_mfma_f32_16x16x32_bf16(af0, bv0, a00, 0, 0, 0);
        a01 = __builtin_amdgcn_mfma_f32_16x16x32_bf16(af0, bv1, a01, 0, 0, 0);
        a02 = __builtin_amdgcn_mfma_f32_16x16x32_bf16(af0, bv2, a02, 0, 0, 0);
        a03 = __builtin_amdgcn_mfma_f32_16x16x32_bf16(af0, bv3, a03, 0, 0, 0);
        a10 = __builtin_amdgcn_mfma_f32_16x16x32_bf16(af1, bv0, a10, 0, 0, 0);
        a11 = __builtin_amdgcn_mfma_f32_16x16x32_bf16(af1, bv1, a11, 0, 0, 0);
        a12 = __builtin_amdgcn_mfma_f32_16x16x32_bf16(af1, bv2, a12, 0, 0, 0);
        a13 = __builtin_amdgcn_mfma_f32_16x16x32_bf16(af1, bv3, a13, 0, 0, 0);
    }

    // D layout: col = lane&15 (+16*nq), row-in-tile = g*4 + reg (+16*m)
    #pragma unroll
    for (int rr = 0; rr < 4; ++rr) {
        const int mr0 = g * 4 + rr, mr1 = 16 + g * 4 + rr;
        hp[wv][mr0][r     ] = a00[rr];
        hp[wv][mr0][r + 16] = a01[rr];
        hp[wv][mr0][r + 32] = a02[rr];
        hp[wv][mr0][r + 48] = a03[rr];
        hp[wv][mr1][r     ] = a10[rr];
        hp[wv][mr1][r + 16] = a11[rr];
        hp[wv][mr1][r + 32] = a12[rr];
        hp[wv][mr1][r + 48] = a13[rr];
    }
    __syncthreads();

    // Reduce over the 8 K-partials, add b1, leaky relu #1
    for (int e = tid; e < BM * HID; e += 512) {
        int row = e >> 6, col = e & 63;
        float v = b1[col];
        #pragma unroll
        for (int p = 0; p < 8; ++p) v += hp[p][row][col];
        hf[row][col] = (v >= 0.f) ? v : 0.1f * v;
    }
    __syncthreads();

    // GEMM2: [32 x 64] @ [64 x 21] + b2, leaky, keep_count mask
    for (int idx = tid; idx < BM * NCLS; idx += 512) {
        int rI = idx / NCLS;
        int c  = idx - rI * NCLS;
        float a2 = b2[c];
        #pragma unroll 8
        for (int col = 0; col < HID; ++col)
            a2 += hf[rI][col] * w2s[col * NCLS + c];
        a2 = (a2 >= 0.f) ? a2 : 0.1f * a2;        // leaky relu #2
        outp[idx] = (s_base + rI < limit) ? a2 : 0.f;
    }
}

extern "C" void kernel_launch(void* const* d_in, const int* in_sizes, int n_in,
                              void* d_out, int out_size, void* d_ws, size_t ws_size,
                              hipStream_t stream) {
    const float* x    = (const float*)d_in[0];
    const float* W1   = (const float*)d_in[1];
    const float* b1   = (const float*)d_in[2];
    const float* W2   = (const float*)d_in[3];
    const float* b2   = (const float*)d_in[4];
    const int*   keep = (const int*)d_in[5];
    float* out = (float*)d_out;

    hipLaunchKernelGGL(pack_w1,    dim3(KSTEPS), dim3(256), 0, stream, W1);
    hipLaunchKernelGGL(fused_main, dim3((64 * SROWS) / BM), dim3(512), 0, stream,
                       x, b1, W2, b2, keep, out);
}